// Round 16
// baseline (414.177 us; speedup 1.0000x reference)
//
#include <hip/hip_runtime.h>
#include <hip/hip_bf16.h>

#define D 128
#define NNODES 16384
#define NEDGES 262144
#define NBATCH 2
#define TE 128

typedef __attribute__((ext_vector_type(8))) short bf16x8;
typedef __attribute__((ext_vector_type(4))) float f32x4;

__device__ __forceinline__ unsigned int pk2bf(float lo, float hi) {
    unsigned int r;
    asm("v_cvt_pk_bf16_f32 %0, %1, %2" : "=v"(r) : "v"(lo), "v"(hi));
    return r;
}

__device__ __forceinline__ unsigned short f2bf(float f) {
    return (unsigned short)pk2bf(f, f);
}

__device__ __forceinline__ float bflo(unsigned int u) {
    return __uint_as_float(u << 16);
}
__device__ __forceinline__ float bfhi(unsigned int u) {
    return __uint_as_float(u & 0xffff0000u);
}

__device__ __forceinline__ bf16x8 pack8(f32x4 a, f32x4 b) {
    typedef __attribute__((ext_vector_type(4))) unsigned int u32x4;
    u32x4 u;
    u.x = pk2bf(a[0], a[1]);
    u.y = pk2bf(a[2], a[3]);
    u.z = pk2bf(b[0], b[1]);
    u.w = pk2bf(b[2], b[3]);
    return __builtin_bit_cast(bf16x8, u);
}

// --------------------------------------------------------------- weight prep
__global__ __launch_bounds__(256)
void prep_weights(const float* __restrict__ We1, const float* __restrict__ We2,
                  const float* __restrict__ Wn1, const float* __restrict__ Wn2,
                  unsigned short* __restrict__ w)
{
    int id = blockIdx.x * 256 + threadIdx.x;   // 114688 total
    if (id < 16384) {
        int e = id & 7, l = (id >> 3) & 63, nblk = (id >> 9) & 7, ks = id >> 12;
        int k = 256 + ks * 32 + ((l >> 4) & 3) * 8 + e;
        int col = nblk * 16 + (l & 15);
        w[id] = f2bf(We1[k * 128 + col]);
    } else if (id < 32768) {
        int i2 = id - 16384;
        int e = i2 & 7, l = (i2 >> 3) & 63, nblk = (i2 >> 9) & 7, ks = i2 >> 12;
        int k = ks * 32 + ((l >> 4) & 3) * 8 + e;
        int col = nblk * 16 + (l & 15);
        w[id] = f2bf(We2[k * 128 + col]);
    } else if (id < 65536) {
        int i3 = id - 32768;
        int j = i3 >> 7, k = i3 & 127;
        int row = (j < 128) ? k : (128 + k);
        w[id] = f2bf(We1[row * 128 + (j & 127)]);
    } else if (id < 98304) {
        int i4 = id - 65536;
        int n = i4 >> 8, k = i4 & 255;
        w[id] = f2bf(Wn1[k * 128 + n]);
    } else {
        int i5 = id - 98304;
        int n = i5 >> 7, k = i5 & 127;
        w[id] = f2bf(Wn2[k * 128 + n]);
    }
}

// ------------------------------------------------------------ partial kernel
// P2[r][pcol] PERMUTED: original col = part*128 + sub*64 + n*16 + l15
// stored at part*128 + sub*64 + l15*4 + n
__global__ __launch_bounds__(256)
void partial_kernel(const float* __restrict__ V, const unsigned short* __restrict__ wp,
                    unsigned short* __restrict__ P)
{
    __shared__ unsigned short smem[64 * 136];
    const int t = threadIdx.x, lane = t & 63, wave = t >> 6;
    const int l15 = lane & 15, l4 = lane >> 4;
    const long long r0 = (long long)blockIdx.x * 64;

    for (int i = t; i < 64 * 32; i += 256) {
        int c4 = i & 31, r = i >> 5;
        float4 v = *(const float4*)(V + (r0 + r) * 128 + c4 * 4);
        uint2 p; p.x = pk2bf(v.x, v.y); p.y = pk2bf(v.z, v.w);
        *(uint2*)(&smem[r * 136 + c4 * 4]) = p;
    }
    __syncthreads();

    const int j0 = wave * 64;
    f32x4 acc[4][4] = {};
    const unsigned short* bb0 = wp + (j0 + l15) * 128 + l4 * 8;
    #pragma unroll
    for (int ks = 0; ks < 4; ++ks) {
        bf16x8 bb[4];
        #pragma unroll
        for (int n = 0; n < 4; ++n)
            bb[n] = *(const bf16x8*)(bb0 + n * 16 * 128 + ks * 32);
        #pragma unroll
        for (int mq = 0; mq < 4; ++mq) {
            bf16x8 a = *(const bf16x8*)(&smem[(mq * 16 + l15) * 136 + l4 * 8 + ks * 32]);
            #pragma unroll
            for (int n = 0; n < 4; ++n)
                acc[mq][n] = __builtin_amdgcn_mfma_f32_16x16x32_bf16(a, bb[n], acc[mq][n], 0, 0, 0);
        }
    }
    const int pbase = (wave >> 1) * 128 + (wave & 1) * 64 + l15 * 4;
    #pragma unroll
    for (int mq = 0; mq < 4; ++mq) {
        #pragma unroll
        for (int i = 0; i < 4; ++i) {
            int row = mq * 16 + l4 * 4 + i;
            uint2 pw;
            pw.x = pk2bf(acc[mq][0][i], acc[mq][1][i]);
            pw.y = pk2bf(acc[mq][2][i], acc[mq][3][i]);
            *(uint2*)(P + (r0 + row) * 256 + pbase) = pw;
        }
    }
}

// ----------------------------------------------------------------- CSR build
__global__ __launch_bounds__(256)
void count_kernel(const int* __restrict__ edges, int* __restrict__ cnt)
{
    int id = blockIdx.x * 256 + threadIdx.x;       // BS*NE = 524288
    int b = id >> 18;
    int2 e = ((const int2*)edges)[id];
    atomicAdd(&cnt[(b << 14) + e.x], 1);
    atomicAdd(&cnt[32768 + (b << 14) + e.y], 1);
}

// exclusive scan of 32768 ints per direction; grid=2 (dir), 1024 threads.
__global__ __launch_bounds__(1024)
void scan_kernel(const int* __restrict__ cnt, int* __restrict__ off, int* __restrict__ cur)
{
    __shared__ int part[1024];
    const int a = blockIdx.x;
    const int t = threadIdx.x;
    const int* c = cnt + a * 32768;
    int* o  = off + a * 32768;
    int* cu = cur + a * 32768;
    int base = t * 32;
    int loc[32];
    int s = 0;
    #pragma unroll
    for (int i = 0; i < 32; ++i) { loc[i] = s; s += c[base + i]; }
    part[t] = s;
    __syncthreads();
    for (int d = 1; d < 1024; d <<= 1) {
        int v = (t >= d) ? part[t - d] : 0;
        __syncthreads();
        part[t] += v;
        __syncthreads();
    }
    int pre = (t == 0) ? 0 : part[t - 1];
    #pragma unroll
    for (int i = 0; i < 32; ++i) {
        int v = pre + loc[i];
        o[base + i]  = v;
        cu[base + i] = v;
    }
}

__global__ __launch_bounds__(256)
void fill_kernel(const int* __restrict__ edges, int* __restrict__ cur,
                 int* __restrict__ idx)
{
    int id = blockIdx.x * 256 + threadIdx.x;       // flat edge id
    int b = id >> 18;
    int2 e = ((const int2*)edges)[id];
    int p0 = atomicAdd(&cur[(b << 14) + e.x], 1);
    idx[p0] = id;
    int p1 = atomicAdd(&cur[32768 + (b << 14) + e.y], 1);
    idx[NBATCH * NEDGES + p1] = id;
}

// ---------------------------------------------------------------- edge kernel
// Both batches in one launch (grid 4096). E global->reg, P early gather,
// single barrier, NO atomics: e0/e1 streamed to linear per-edge buffers.
__global__ __launch_bounds__(512)
void edge_kernel(const float* __restrict__ E, const int* __restrict__ edges,
                 const unsigned short* __restrict__ P,
                 const unsigned short* __restrict__ w1ef, const float* __restrict__ be1,
                 const unsigned short* __restrict__ w2f,
                 unsigned short* __restrict__ out0, unsigned short* __restrict__ out1)
{
    __shared__ unsigned short Hbuf[TE * 136];

    const int t    = threadIdx.x;
    const int lane = t & 63;
    const int wave = t >> 6;
    const int wr   = wave >> 1;
    const int wc   = wave & 1;
    const int l15  = lane & 15;
    const int l4   = lane >> 4;

    const long long eflat0 = (long long)blockIdx.x * TE;
    const int b  = (int)(eflat0 / NEDGES);
    const long long nb0 = (long long)b * NNODES;

    // node indices
    int nd0[2][4], nd1[2][4];
    #pragma unroll
    for (int m = 0; m < 2; ++m) {
        #pragma unroll
        for (int i = 0; i < 4; ++i) {
            int row = wr * 32 + m * 16 + l4 * 4 + i;
            int2 e2 = *(const int2*)(edges + (eflat0 + row) * 2);
            nd0[m][i] = e2.x;
            nd1[m][i] = e2.y;
        }
    }

    // P gathers (permuted layout)
    const unsigned short* Pb = P + nb0 * 256;
    const unsigned int wcl = wc * 64 + l15 * 4;
    uint2 su[2][4], ru[2][4];
    #pragma unroll
    for (int m = 0; m < 2; ++m) {
        #pragma unroll
        for (int i = 0; i < 4; ++i) {
            su[m][i] = *(const uint2*)(Pb + (unsigned)nd0[m][i] * 256u + wcl);
            ru[m][i] = *(const uint2*)(Pb + (unsigned)nd1[m][i] * 256u + 128u + wcl);
        }
    }

    // layer 1 (E part): [128x128] @ [128x128]
    f32x4 acc[2][4] = {};
    {
        const float* er0 = E + (eflat0 + wr * 32 + l15) * D + l4 * 8;
        #pragma unroll
        for (int ks = 0; ks < 4; ++ks) {
            f32x4 xa0 = *(const f32x4*)(er0 + ks * 32);
            f32x4 xb0 = *(const f32x4*)(er0 + ks * 32 + 4);
            f32x4 xa1 = *(const f32x4*)(er0 + 16 * D + ks * 32);
            f32x4 xb1 = *(const f32x4*)(er0 + 16 * D + ks * 32 + 4);
            bf16x8 a0 = pack8(xa0, xb0);
            bf16x8 a1 = pack8(xa1, xb1);
            #pragma unroll
            for (int n = 0; n < 4; ++n) {
                bf16x8 bb = *(const bf16x8*)(w1ef + (((ks * 8 + wc * 4 + n) * 64 + lane) << 3));
                acc[0][n] = __builtin_amdgcn_mfma_f32_16x16x32_bf16(a0, bb, acc[0][n], 0, 0, 0);
                acc[1][n] = __builtin_amdgcn_mfma_f32_16x16x32_bf16(a1, bb, acc[1][n], 0, 0, 0);
            }
        }
    }

    // epilogue: + P_s + P_r + bias, silu -> Hbuf
    float bia[4];
    #pragma unroll
    for (int n = 0; n < 4; ++n) bia[n] = be1[wc * 64 + n * 16 + l15];
    #pragma unroll
    for (int m = 0; m < 2; ++m) {
        #pragma unroll
        for (int i = 0; i < 4; ++i) {
            int row = wr * 32 + m * 16 + l4 * 4 + i;
            float ps[4] = { bflo(su[m][i].x), bfhi(su[m][i].x),
                            bflo(su[m][i].y), bfhi(su[m][i].y) };
            float pr[4] = { bflo(ru[m][i].x), bfhi(ru[m][i].x),
                            bflo(ru[m][i].y), bfhi(ru[m][i].y) };
            #pragma unroll
            for (int n = 0; n < 4; ++n) {
                float a = acc[m][n][i] + bia[n] + ps[n] + pr[n];
                Hbuf[row * 136 + wc * 64 + n * 16 + l15] = f2bf(a / (1.f + __expf(-a)));
            }
        }
    }
    __syncthreads();

    // layer 2: [128x128] @ [128x128]
    f32x4 acc2[2][4] = {};
    {
        const unsigned short* hrow = &Hbuf[(wr * 32 + l15) * 136 + l4 * 8];
        #pragma unroll
        for (int ks = 0; ks < 4; ++ks) {
            bf16x8 a0 = *(const bf16x8*)(hrow + ks * 32);
            bf16x8 a1 = *(const bf16x8*)(hrow + 16 * 136 + ks * 32);
            #pragma unroll
            for (int n = 0; n < 4; ++n) {
                bf16x8 bb = *(const bf16x8*)(w2f + (((ks * 8 + wc * 4 + n) * 64 + lane) << 3));
                acc2[0][n] = __builtin_amdgcn_mfma_f32_16x16x32_bf16(a0, bb, acc2[0][n], 0, 0, 0);
                acc2[1][n] = __builtin_amdgcn_mfma_f32_16x16x32_bf16(a1, bb, acc2[1][n], 0, 0, 0);
            }
        }
    }

    // linear streaming writes: e0 -> out0[edge][64], e1 -> out1 (flat edge id)
    {
        unsigned short* dst = wc ? out1 : out0;
        #pragma unroll
        for (int n = 0; n < 4; ++n) {
            int colh = n * 16 + l15;
            #pragma unroll
            for (int m = 0; m < 2; ++m) {
                #pragma unroll
                for (int i = 0; i < 4; ++i) {
                    long long lrow = eflat0 + wr * 32 + m * 16 + l4 * 4 + i;
                    float v  = acc2[m][n][i];
                    float vn = __shfl_xor(v, 1);
                    if (!(lane & 1)) {
                        *(unsigned int*)(dst + lrow * 64 + colh) = pk2bf(v, vn);
                    }
                }
            }
        }
    }
}

// --------------------------------------------------------------- gather mean
// Both batches in one launch: 65536 (node,dir) groups, 16 lanes each.
// 4-deep pipelined CSR sum (4 independent idx->row load chains in flight).
__global__ __launch_bounds__(256)
void gather_kernel(const unsigned short* __restrict__ out0,
                   const unsigned short* __restrict__ out1,
                   const int* __restrict__ idx, const int* __restrict__ off,
                   const int* __restrict__ cnt, const float* __restrict__ be2,
                   unsigned short* __restrict__ m0, unsigned short* __restrict__ m1)
{
    const int t = threadIdx.x;
    const int grp = t >> 4, l = t & 15;
    int gid = blockIdx.x * 16 + grp;          // 0..65535
    int dir = gid >> 15;
    int nf  = gid & 32767;                    // flat b*N+n

    int o = off[dir * 32768 + nf];
    int c = cnt[dir * 32768 + nf];
    const unsigned short* src = dir ? out1 : out0;
    const int* ix = idx + (long long)dir * (NBATCH * NEDGES);

    float a0 = 0.f, a1 = 0.f, a2 = 0.f, a3 = 0.f;
    int j = 0;
    for (; j + 4 <= c; j += 4) {
        int e0 = ix[o + j], e1 = ix[o + j + 1], e2 = ix[o + j + 2], e3 = ix[o + j + 3];
        uint2 v0 = *(const uint2*)(src + (long long)e0 * 64 + l * 4);
        uint2 v1 = *(const uint2*)(src + (long long)e1 * 64 + l * 4);
        uint2 v2 = *(const uint2*)(src + (long long)e2 * 64 + l * 4);
        uint2 v3 = *(const uint2*)(src + (long long)e3 * 64 + l * 4);
        a0 += bflo(v0.x) + bflo(v1.x) + bflo(v2.x) + bflo(v3.x);
        a1 += bfhi(v0.x) + bfhi(v1.x) + bfhi(v2.x) + bfhi(v3.x);
        a2 += bflo(v0.y) + bflo(v1.y) + bflo(v2.y) + bflo(v3.y);
        a3 += bfhi(v0.y) + bfhi(v1.y) + bfhi(v2.y) + bfhi(v3.y);
    }
    for (; j < c; ++j) {
        int eid = ix[o + j];
        uint2 v = *(const uint2*)(src + (long long)eid * 64 + l * 4);
        a0 += bflo(v.x); a1 += bfhi(v.x);
        a2 += bflo(v.y); a3 += bfhi(v.y);
    }
    float inv  = (c > 0) ? (1.f / (float)c) : 0.f;
    float gate = (c > 0) ? 1.f : 0.f;
    const float* bb = be2 + dir * 64 + l * 4;
    a0 = a0 * inv + bb[0] * gate;
    a1 = a1 * inv + bb[1] * gate;
    a2 = a2 * inv + bb[2] * gate;
    a3 = a3 * inv + bb[3] * gate;
    uint2 w;
    w.x = pk2bf(a0, a1);
    w.y = pk2bf(a2, a3);
    *(uint2*)((dir ? m1 : m0) + (long long)nf * 64 + l * 4) = w;
}

// ---------------------------------------------------------------- node kernel
// m0/m1 are READY means (be2 included); staging is a straight copy.
__global__ __launch_bounds__(256)
void node_kernel(const float* __restrict__ V,
                 const unsigned short* __restrict__ m0, const unsigned short* __restrict__ m1,
                 const unsigned short* __restrict__ wn1t, const float* __restrict__ bn1,
                 const unsigned short* __restrict__ wn2t, const float* __restrict__ bn2,
                 float* __restrict__ node_emb)
{
    __shared__ unsigned short smem[64 * 264];   // A [64][264]; reused as H [64][136]

    const int t    = threadIdx.x;
    const int lane = t & 63;
    const int wave = t >> 6;
    const int wr   = wave >> 1;
    const int wc   = wave & 1;
    const int l15  = lane & 15;
    const int l4   = lane >> 4;

    const long long nflat0 = (long long)blockIdx.x * 64;

    for (int i = t; i < 64 * 48; i += 256) {
        int n  = i / 48;
        int c4 = i - n * 48;
        long long node = nflat0 + n;
        if (c4 < 32) {
            float4 v = *(const float4*)(V + node * 128 + c4 * 4);
            uint2 p; p.x = pk2bf(v.x, v.y); p.y = pk2bf(v.z, v.w);
            *(uint2*)(&smem[n * 264 + c4 * 4]) = p;
        } else {
            int dir = (c4 >= 40);
            int j = c4 - 32 - dir * 8;
            const unsigned short* src = dir ? m1 : m0;
            uint4 raw = *(const uint4*)(src + node * 64 + j * 8);
            *(uint4*)(&smem[n * 264 + 128 + dir * 64 + j * 8]) = raw;
        }
    }
    __syncthreads();

    f32x4 acc[2][4] = {};
    {
        const unsigned short* arow = &smem[(wr * 32 + l15) * 264 + l4 * 8];
        const unsigned short* bb0  = wn1t + (wc * 64 + l15) * 256 + l4 * 8;
        for (int ks = 0; ks < 8; ++ks) {
            bf16x8 a0 = *(const bf16x8*)(arow + ks * 32);
            bf16x8 a1 = *(const bf16x8*)(arow + 16 * 264 + ks * 32);
            #pragma unroll
            for (int n = 0; n < 4; ++n) {
                bf16x8 bb = *(const bf16x8*)(bb0 + n * 16 * 256 + ks * 32);
                acc[0][n] = __builtin_amdgcn_mfma_f32_16x16x32_bf16(a0, bb, acc[0][n], 0, 0, 0);
                acc[1][n] = __builtin_amdgcn_mfma_f32_16x16x32_bf16(a1, bb, acc[1][n], 0, 0, 0);
            }
        }
    }
    __syncthreads();

    #pragma unroll
    for (int n = 0; n < 4; ++n) {
        int col = wc * 64 + n * 16 + l15;
        float bias = bn1[col];
        #pragma unroll
        for (int m = 0; m < 2; ++m) {
            #pragma unroll
            for (int i = 0; i < 4; ++i) {
                int row = wr * 32 + m * 16 + l4 * 4 + i;
                float a = acc[m][n][i] + bias;
                smem[row * 136 + col] = f2bf(a / (1.f + __expf(-a)));
            }
        }
    }
    __syncthreads();

    f32x4 acc2[2][4] = {};
    {
        const unsigned short* hrow = &smem[(wr * 32 + l15) * 136 + l4 * 8];
        const unsigned short* bb0  = wn2t + (wc * 64 + l15) * 128 + l4 * 8;
        #pragma unroll
        for (int ks = 0; ks < 4; ++ks) {
            bf16x8 a0 = *(const bf16x8*)(hrow + ks * 32);
            bf16x8 a1 = *(const bf16x8*)(hrow + 16 * 136 + ks * 32);
            #pragma unroll
            for (int n = 0; n < 4; ++n) {
                bf16x8 bb = *(const bf16x8*)(bb0 + n * 16 * 128 + ks * 32);
                acc2[0][n] = __builtin_amdgcn_mfma_f32_16x16x32_bf16(a0, bb, acc2[0][n], 0, 0, 0);
                acc2[1][n] = __builtin_amdgcn_mfma_f32_16x16x32_bf16(a1, bb, acc2[1][n], 0, 0, 0);
            }
        }
    }

    #pragma unroll
    for (int n = 0; n < 4; ++n) {
        int col = wc * 64 + n * 16 + l15;
        float bias = bn2[col];
        #pragma unroll
        for (int m = 0; m < 2; ++m) {
            #pragma unroll
            for (int i = 0; i < 4; ++i) {
                long long row = nflat0 + wr * 32 + m * 16 + l4 * 4 + i;
                node_emb[row * 128 + col] = acc2[m][n][i] + bias;
            }
        }
    }
}

// ------------------------------------------------------------ attention kernel
__global__ __launch_bounds__(256)
void attn_kernel(const float* __restrict__ blocks, const float* __restrict__ node_emb,
                 const float* __restrict__ w_attn, const float* __restrict__ rms_w,
                 float* __restrict__ out)
{
    const int t    = threadIdx.x;
    const int wave = t >> 6;
    const int lane = t & 63;
    const long long node = (long long)blockIdx.x * 4 + wave;
    const int d0 = lane * 2;

    float2 wa = *(const float2*)(w_attn + d0);
    float2 rw = *(const float2*)(rms_w + d0);

    float xs[5][2];
    float lg[5];
    #pragma unroll
    for (int s = 0; s < 5; ++s) {
        const float* src = (s < 4)
            ? (blocks + ((long long)s * NBATCH * NNODES + node) * 128)
            : (node_emb + node * 128);
        float2 x = *(const float2*)(src + d0);
        xs[s][0] = x.x; xs[s][1] = x.y;
        float ss = x.x * x.x + x.y * x.y;
        float wv = wa.x * rw.x * x.x + wa.y * rw.y * x.y;
        #pragma unroll
        for (int m = 1; m < 64; m <<= 1) {
            ss += __shfl_xor(ss, m);
            wv += __shfl_xor(wv, m);
        }
        lg[s] = wv * rsqrtf(ss * (1.f / 128.f) + 1e-6f);
    }

    float mx = lg[0];
    #pragma unroll
    for (int s = 1; s < 5; ++s) mx = fmaxf(mx, lg[s]);
    float ex[5], sum = 0.f;
    #pragma unroll
    for (int s = 0; s < 5; ++s) { ex[s] = __expf(lg[s] - mx); sum += ex[s]; }
    float inv = 1.f / sum;

    float h0 = 0.f, h1 = 0.f;
    #pragma unroll
    for (int s = 0; s < 5; ++s) {
        float a = ex[s] * inv;
        h0 = fmaf(a, xs[s][0], h0);
        h1 = fmaf(a, xs[s][1], h1);
    }
    *(float2*)(out + node * 128 + d0) = make_float2(h0, h1);
}

// ------------------------------------------------------------------- launcher
extern "C" void kernel_launch(void* const* d_in, const int* in_sizes, int n_in,
                              void* d_out, int out_size, void* d_ws, size_t ws_size,
                              hipStream_t stream)
{
    const float* V      = (const float*)d_in[0];
    const float* E      = (const float*)d_in[1];
    const float* blocks = (const float*)d_in[2];
    const float* We1    = (const float*)d_in[3];
    const float* be1    = (const float*)d_in[4];
    const float* We2    = (const float*)d_in[5];
    const float* be2    = (const float*)d_in[6];
    const float* Wn1    = (const float*)d_in[7];
    const float* bn1    = (const float*)d_in[8];
    const float* Wn2    = (const float*)d_in[9];
    const float* bn2    = (const float*)d_in[10];
    const float* w_attn = (const float*)d_in[11];
    const float* rms_w  = (const float*)d_in[12];
    const int*   edges  = (const int*)d_in[13];
    float* out = (float*)d_out;

    // ws layout (~180 MB):
    // [cnt 256KB][cur 256KB][off 256KB][idx 4MB][m0 4MB][m1 4MB][wbf 224KB]
    // [P 16.8MB][out0 67MB][out1 67MB][node_emb 16.8MB]
    int* cnti = (int*)d_ws;                         // 65536
    int* cur  = cnti + 65536;
    int* offi = cur + 65536;
    int* idx  = offi + 65536;                       // 2*524288 ints
    unsigned short* m0  = (unsigned short*)(idx + 2 * NBATCH * NEDGES);
    unsigned short* m1  = m0 + 2097152;
    unsigned short* wbf = m1 + 2097152;             // 114688
    unsigned short* w1ef = wbf;
    unsigned short* w2f  = wbf + 16384;
    unsigned short* wp   = wbf + 32768;
    unsigned short* wn1t = wbf + 65536;
    unsigned short* wn2t = wbf + 98304;
    unsigned short* P    = wbf + 114688;            // 8388608
    unsigned short* out0 = P + 8388608;             // NBATCH*NEDGES*64
    unsigned short* out1 = out0 + (size_t)NBATCH * NEDGES * 64;
    float* node_emb = (float*)(out1 + (size_t)NBATCH * NEDGES * 64);

    // zero edge-count histogram only
    (void)hipMemsetAsync(cnti, 0, 65536 * sizeof(int), stream);

    prep_weights<<<448, 256, 0, stream>>>(We1, We2, Wn1, Wn2, wbf);

    partial_kernel<<<(NBATCH * NNODES) / 64, 256, 0, stream>>>(V, wp, P);

    // CSR build
    count_kernel<<<(NBATCH * NEDGES) / 256, 256, 0, stream>>>(edges, cnti);
    scan_kernel<<<2, 1024, 0, stream>>>(cnti, offi, cur);
    fill_kernel<<<(NBATCH * NEDGES) / 256, 256, 0, stream>>>(edges, cur, idx);

    // edge MLP (both batches, linear out) -> gather means (both batches)
    edge_kernel<<<(NBATCH * NEDGES) / TE, 512, 0, stream>>>(
        E, edges, P, w1ef, be1, w2f, out0, out1);
    gather_kernel<<<4096, 256, 0, stream>>>(
        out0, out1, idx, offi, cnti, be2, m0, m1);

    node_kernel<<<(NBATCH * NNODES) / 64, 256, 0, stream>>>(
        V, m0, m1, wn1t, bn1, wn2t, bn2, node_emb);

    attn_kernel<<<(NBATCH * NNODES) / 4, 256, 0, stream>>>(
        blocks, node_emb, w_attn, rms_w, out);
}

// Round 18
// 406.319 us; speedup vs baseline: 1.0193x; 1.0193x over previous
//
#include <hip/hip_runtime.h>
#include <hip/hip_bf16.h>

#define D 128
#define NNODES 16384
#define NEDGES 262144
#define NBATCH 2
#define TE 128

typedef __attribute__((ext_vector_type(8))) short bf16x8;
typedef __attribute__((ext_vector_type(4))) float f32x4;

__device__ __forceinline__ unsigned int pk2bf(float lo, float hi) {
    unsigned int r;
    asm("v_cvt_pk_bf16_f32 %0, %1, %2" : "=v"(r) : "v"(lo), "v"(hi));
    return r;
}

__device__ __forceinline__ unsigned short f2bf(float f) {
    return (unsigned short)pk2bf(f, f);
}

__device__ __forceinline__ float bflo(unsigned int u) {
    return __uint_as_float(u << 16);
}
__device__ __forceinline__ float bfhi(unsigned int u) {
    return __uint_as_float(u & 0xffff0000u);
}

__device__ __forceinline__ bf16x8 pack8(f32x4 a, f32x4 b) {
    typedef __attribute__((ext_vector_type(4))) unsigned int u32x4;
    u32x4 u;
    u.x = pk2bf(a[0], a[1]);
    u.y = pk2bf(a[2], a[3]);
    u.z = pk2bf(b[0], b[1]);
    u.w = pk2bf(b[2], b[3]);
    return __builtin_bit_cast(bf16x8, u);
}

// --------------------------------------------------------------- weight prep
__global__ __launch_bounds__(256)
void prep_weights(const float* __restrict__ We1, const float* __restrict__ We2,
                  const float* __restrict__ Wn1, const float* __restrict__ Wn2,
                  unsigned short* __restrict__ w)
{
    int id = blockIdx.x * 256 + threadIdx.x;   // 114688 total
    if (id < 16384) {
        int e = id & 7, l = (id >> 3) & 63, nblk = (id >> 9) & 7, ks = id >> 12;
        int k = 256 + ks * 32 + ((l >> 4) & 3) * 8 + e;
        int col = nblk * 16 + (l & 15);
        w[id] = f2bf(We1[k * 128 + col]);
    } else if (id < 32768) {
        int i2 = id - 16384;
        int e = i2 & 7, l = (i2 >> 3) & 63, nblk = (i2 >> 9) & 7, ks = i2 >> 12;
        int k = ks * 32 + ((l >> 4) & 3) * 8 + e;
        int col = nblk * 16 + (l & 15);
        w[id] = f2bf(We2[k * 128 + col]);
    } else if (id < 65536) {
        int i3 = id - 32768;
        int j = i3 >> 7, k = i3 & 127;
        int row = (j < 128) ? k : (128 + k);
        w[id] = f2bf(We1[row * 128 + (j & 127)]);
    } else if (id < 98304) {
        int i4 = id - 65536;
        int n = i4 >> 8, k = i4 & 255;
        w[id] = f2bf(Wn1[k * 128 + n]);
    } else {
        int i5 = id - 98304;
        int n = i5 >> 7, k = i5 & 127;
        w[id] = f2bf(Wn2[k * 128 + n]);
    }
}

// ------------------------------------------------------------ partial kernel
// P2[r][pcol] PERMUTED: original col = part*128 + sub*64 + n*16 + l15
// stored at part*128 + sub*64 + l15*4 + n
__global__ __launch_bounds__(256)
void partial_kernel(const float* __restrict__ V, const unsigned short* __restrict__ wp,
                    unsigned short* __restrict__ P)
{
    __shared__ unsigned short smem[64 * 136];
    const int t = threadIdx.x, lane = t & 63, wave = t >> 6;
    const int l15 = lane & 15, l4 = lane >> 4;
    const long long r0 = (long long)blockIdx.x * 64;

    for (int i = t; i < 64 * 32; i += 256) {
        int c4 = i & 31, r = i >> 5;
        float4 v = *(const float4*)(V + (r0 + r) * 128 + c4 * 4);
        uint2 p; p.x = pk2bf(v.x, v.y); p.y = pk2bf(v.z, v.w);
        *(uint2*)(&smem[r * 136 + c4 * 4]) = p;
    }
    __syncthreads();

    const int j0 = wave * 64;
    f32x4 acc[4][4] = {};
    const unsigned short* bb0 = wp + (j0 + l15) * 128 + l4 * 8;
    #pragma unroll
    for (int ks = 0; ks < 4; ++ks) {
        bf16x8 bb[4];
        #pragma unroll
        for (int n = 0; n < 4; ++n)
            bb[n] = *(const bf16x8*)(bb0 + n * 16 * 128 + ks * 32);
        #pragma unroll
        for (int mq = 0; mq < 4; ++mq) {
            bf16x8 a = *(const bf16x8*)(&smem[(mq * 16 + l15) * 136 + l4 * 8 + ks * 32]);
            #pragma unroll
            for (int n = 0; n < 4; ++n)
                acc[mq][n] = __builtin_amdgcn_mfma_f32_16x16x32_bf16(a, bb[n], acc[mq][n], 0, 0, 0);
        }
    }
    const int pbase = (wave >> 1) * 128 + (wave & 1) * 64 + l15 * 4;
    #pragma unroll
    for (int mq = 0; mq < 4; ++mq) {
        #pragma unroll
        for (int i = 0; i < 4; ++i) {
            int row = mq * 16 + l4 * 4 + i;
            uint2 pw;
            pw.x = pk2bf(acc[mq][0][i], acc[mq][1][i]);
            pw.y = pk2bf(acc[mq][2][i], acc[mq][3][i]);
            *(uint2*)(P + (r0 + row) * 256 + pbase) = pw;
        }
    }
}

// ----------------------------------------------------------------- CSR build
__global__ __launch_bounds__(256)
void count_kernel(const int* __restrict__ edges, int* __restrict__ cnt)
{
    int id = blockIdx.x * 256 + threadIdx.x;       // BS*NE = 524288
    int b = id >> 18;
    int2 e = ((const int2*)edges)[id];
    atomicAdd(&cnt[(b << 14) + e.x], 1);
    atomicAdd(&cnt[32768 + (b << 14) + e.y], 1);
}

// exclusive scan of 32768 ints per direction; grid=2 (dir), 1024 threads.
__global__ __launch_bounds__(1024)
void scan_kernel(const int* __restrict__ cnt, int* __restrict__ off, int* __restrict__ cur)
{
    __shared__ int part[1024];
    const int a = blockIdx.x;
    const int t = threadIdx.x;
    const int* c = cnt + a * 32768;
    int* o  = off + a * 32768;
    int* cu = cur + a * 32768;
    int base = t * 32;
    int loc[32];
    int s = 0;
    #pragma unroll
    for (int i = 0; i < 32; ++i) { loc[i] = s; s += c[base + i]; }
    part[t] = s;
    __syncthreads();
    for (int d = 1; d < 1024; d <<= 1) {
        int v = (t >= d) ? part[t - d] : 0;
        __syncthreads();
        part[t] += v;
        __syncthreads();
    }
    int pre = (t == 0) ? 0 : part[t - 1];
    #pragma unroll
    for (int i = 0; i < 32; ++i) {
        int v = pre + loc[i];
        o[base + i]  = v;
        cu[base + i] = v;
    }
}

// Writes each edge's CSR slot (pos0 for its sender list, pos1 for receiver).
__global__ __launch_bounds__(256)
void fill_kernel(const int* __restrict__ edges, int* __restrict__ cur,
                 int* __restrict__ pos0, int* __restrict__ pos1)
{
    int id = blockIdx.x * 256 + threadIdx.x;       // flat edge id
    int b = id >> 18;
    int2 e = ((const int2*)edges)[id];
    pos0[id] = atomicAdd(&cur[(b << 14) + e.x], 1);
    pos1[id] = atomicAdd(&cur[32768 + (b << 14) + e.y], 1);
}

// ---------------------------------------------------------------- edge kernel
// r16-proven body (combined P gathers, plain launch_bounds(512)).
// Outputs written in CSR ORDER (row = pos[edge]) -> gather reads contiguous.
__global__ __launch_bounds__(512)
void edge_kernel(const float* __restrict__ E, const int* __restrict__ edges,
                 const unsigned short* __restrict__ P,
                 const unsigned short* __restrict__ w1ef, const float* __restrict__ be1,
                 const unsigned short* __restrict__ w2f,
                 const int* __restrict__ pos0, const int* __restrict__ pos1,
                 unsigned short* __restrict__ out0, unsigned short* __restrict__ out1)
{
    __shared__ unsigned short Hbuf[TE * 136];

    const int t    = threadIdx.x;
    const int lane = t & 63;
    const int wave = t >> 6;
    const int wr   = wave >> 1;
    const int wc   = wave & 1;
    const int l15  = lane & 15;
    const int l4   = lane >> 4;

    const long long eflat0 = (long long)blockIdx.x * TE;
    const int b  = (int)(eflat0 / NEDGES);
    const long long nb0 = (long long)b * NNODES;

    // node indices
    int nd0[2][4], nd1[2][4];
    #pragma unroll
    for (int m = 0; m < 2; ++m) {
        #pragma unroll
        for (int i = 0; i < 4; ++i) {
            int row = wr * 32 + m * 16 + l4 * 4 + i;
            int2 e2 = *(const int2*)(edges + (eflat0 + row) * 2);
            nd0[m][i] = e2.x;
            nd1[m][i] = e2.y;
        }
    }

    // P gathers (permuted layout)
    const unsigned short* Pb = P + nb0 * 256;
    const unsigned int wcl = wc * 64 + l15 * 4;
    uint2 su[2][4], ru[2][4];
    #pragma unroll
    for (int m = 0; m < 2; ++m) {
        #pragma unroll
        for (int i = 0; i < 4; ++i) {
            su[m][i] = *(const uint2*)(Pb + (unsigned)nd0[m][i] * 256u + wcl);
            ru[m][i] = *(const uint2*)(Pb + (unsigned)nd1[m][i] * 256u + 128u + wcl);
        }
    }

    // layer 1 (E part): [128x128] @ [128x128]
    f32x4 acc[2][4] = {};
    {
        const float* er0 = E + (eflat0 + wr * 32 + l15) * D + l4 * 8;
        #pragma unroll
        for (int ks = 0; ks < 4; ++ks) {
            f32x4 xa0 = *(const f32x4*)(er0 + ks * 32);
            f32x4 xb0 = *(const f32x4*)(er0 + ks * 32 + 4);
            f32x4 xa1 = *(const f32x4*)(er0 + 16 * D + ks * 32);
            f32x4 xb1 = *(const f32x4*)(er0 + 16 * D + ks * 32 + 4);
            bf16x8 a0 = pack8(xa0, xb0);
            bf16x8 a1 = pack8(xa1, xb1);
            #pragma unroll
            for (int n = 0; n < 4; ++n) {
                bf16x8 bb = *(const bf16x8*)(w1ef + (((ks * 8 + wc * 4 + n) * 64 + lane) << 3));
                acc[0][n] = __builtin_amdgcn_mfma_f32_16x16x32_bf16(a0, bb, acc[0][n], 0, 0, 0);
                acc[1][n] = __builtin_amdgcn_mfma_f32_16x16x32_bf16(a1, bb, acc[1][n], 0, 0, 0);
            }
        }
    }

    // epilogue: + P_s + P_r + bias, silu -> Hbuf
    float bia[4];
    #pragma unroll
    for (int n = 0; n < 4; ++n) bia[n] = be1[wc * 64 + n * 16 + l15];
    #pragma unroll
    for (int m = 0; m < 2; ++m) {
        #pragma unroll
        for (int i = 0; i < 4; ++i) {
            int row = wr * 32 + m * 16 + l4 * 4 + i;
            float ps[4] = { bflo(su[m][i].x), bfhi(su[m][i].x),
                            bflo(su[m][i].y), bfhi(su[m][i].y) };
            float pr[4] = { bflo(ru[m][i].x), bfhi(ru[m][i].x),
                            bflo(ru[m][i].y), bfhi(ru[m][i].y) };
            #pragma unroll
            for (int n = 0; n < 4; ++n) {
                float a = acc[m][n][i] + bia[n] + ps[n] + pr[n];
                Hbuf[row * 136 + wc * 64 + n * 16 + l15] = f2bf(a / (1.f + __expf(-a)));
            }
        }
    }
    __syncthreads();

    // layer 2: [128x128] @ [128x128]
    f32x4 acc2[2][4] = {};
    {
        const unsigned short* hrow = &Hbuf[(wr * 32 + l15) * 136 + l4 * 8];
        #pragma unroll
        for (int ks = 0; ks < 4; ++ks) {
            bf16x8 a0 = *(const bf16x8*)(hrow + ks * 32);
            bf16x8 a1 = *(const bf16x8*)(hrow + 16 * 136 + ks * 32);
            #pragma unroll
            for (int n = 0; n < 4; ++n) {
                bf16x8 bb = *(const bf16x8*)(w2f + (((ks * 8 + wc * 4 + n) * 64 + lane) << 3));
                acc2[0][n] = __builtin_amdgcn_mfma_f32_16x16x32_bf16(a0, bb, acc2[0][n], 0, 0, 0);
                acc2[1][n] = __builtin_amdgcn_mfma_f32_16x16x32_bf16(a1, bb, acc2[1][n], 0, 0, 0);
            }
        }
    }

    // CSR-ordered streaming writes (no atomics, no RMW): row = pos[edge].
    // 16-lane group writes 32B contiguous per n; pieces of the same 128B row
    // arrive together -> L2 write-combines to full lines.
    {
        unsigned short* dst = wc ? out1 : out0;
        const int* pos = wc ? pos1 : pos0;
        #pragma unroll
        for (int m = 0; m < 2; ++m) {
            #pragma unroll
            for (int i = 0; i < 4; ++i) {
                int row = wr * 32 + m * 16 + l4 * 4 + i;
                long long slot = pos[eflat0 + row];   // same addr for 16 lanes -> broadcast
                #pragma unroll
                for (int n = 0; n < 4; ++n) {
                    int colh = n * 16 + l15;
                    float v  = acc2[m][n][i];
                    float vn = __shfl_xor(v, 1);
                    if (!(lane & 1)) {
                        *(unsigned int*)(dst + slot * 64 + colh) = pk2bf(v, vn);
                    }
                }
            }
        }
    }
}

// --------------------------------------------------------------- gather mean
// CSR-ordered inputs -> each (node,dir) group's rows are CONTIGUOUS:
// pure sequential streaming sum, no index chasing.
__global__ __launch_bounds__(256)
void gather_kernel(const unsigned short* __restrict__ out0,
                   const unsigned short* __restrict__ out1,
                   const int* __restrict__ off,
                   const int* __restrict__ cnt, const float* __restrict__ be2,
                   unsigned short* __restrict__ m0, unsigned short* __restrict__ m1)
{
    const int t = threadIdx.x;
    const int grp = t >> 4, l = t & 15;
    int gid = blockIdx.x * 16 + grp;          // 0..65535
    int dir = gid >> 15;
    int nf  = gid & 32767;                    // flat b*N+n

    int o = off[dir * 32768 + nf];
    int c = cnt[dir * 32768 + nf];
    const unsigned short* src = (dir ? out1 : out0) + (long long)o * 64 + l * 4;

    float a0 = 0.f, a1 = 0.f, a2 = 0.f, a3 = 0.f;
    int j = 0;
    for (; j + 4 <= c; j += 4) {
        uint2 v0 = *(const uint2*)(src + (long long)(j + 0) * 64);
        uint2 v1 = *(const uint2*)(src + (long long)(j + 1) * 64);
        uint2 v2 = *(const uint2*)(src + (long long)(j + 2) * 64);
        uint2 v3 = *(const uint2*)(src + (long long)(j + 3) * 64);
        a0 += bflo(v0.x) + bflo(v1.x) + bflo(v2.x) + bflo(v3.x);
        a1 += bfhi(v0.x) + bfhi(v1.x) + bfhi(v2.x) + bfhi(v3.x);
        a2 += bflo(v0.y) + bflo(v1.y) + bflo(v2.y) + bflo(v3.y);
        a3 += bfhi(v0.y) + bfhi(v1.y) + bfhi(v2.y) + bfhi(v3.y);
    }
    for (; j < c; ++j) {
        uint2 v = *(const uint2*)(src + (long long)j * 64);
        a0 += bflo(v.x); a1 += bfhi(v.x);
        a2 += bflo(v.y); a3 += bfhi(v.y);
    }
    float inv  = (c > 0) ? (1.f / (float)c) : 0.f;
    float gate = (c > 0) ? 1.f : 0.f;
    const float* bb = be2 + dir * 64 + l * 4;
    a0 = a0 * inv + bb[0] * gate;
    a1 = a1 * inv + bb[1] * gate;
    a2 = a2 * inv + bb[2] * gate;
    a3 = a3 * inv + bb[3] * gate;
    uint2 w;
    w.x = pk2bf(a0, a1);
    w.y = pk2bf(a2, a3);
    *(uint2*)((dir ? m1 : m0) + (long long)nf * 64 + l * 4) = w;
}

// ---------------------------------------------------------------- node kernel
// m0/m1 are READY means (be2 included); staging is a straight copy.
__global__ __launch_bounds__(256)
void node_kernel(const float* __restrict__ V,
                 const unsigned short* __restrict__ m0, const unsigned short* __restrict__ m1,
                 const unsigned short* __restrict__ wn1t, const float* __restrict__ bn1,
                 const unsigned short* __restrict__ wn2t, const float* __restrict__ bn2,
                 float* __restrict__ node_emb)
{
    __shared__ unsigned short smem[64 * 264];   // A [64][264]; reused as H [64][136]

    const int t    = threadIdx.x;
    const int lane = t & 63;
    const int wave = t >> 6;
    const int wr   = wave >> 1;
    const int wc   = wave & 1;
    const int l15  = lane & 15;
    const int l4   = lane >> 4;

    const long long nflat0 = (long long)blockIdx.x * 64;

    for (int i = t; i < 64 * 48; i += 256) {
        int n  = i / 48;
        int c4 = i - n * 48;
        long long node = nflat0 + n;
        if (c4 < 32) {
            float4 v = *(const float4*)(V + node * 128 + c4 * 4);
            uint2 p; p.x = pk2bf(v.x, v.y); p.y = pk2bf(v.z, v.w);
            *(uint2*)(&smem[n * 264 + c4 * 4]) = p;
        } else {
            int dir = (c4 >= 40);
            int j = c4 - 32 - dir * 8;
            const unsigned short* src = dir ? m1 : m0;
            uint4 raw = *(const uint4*)(src + node * 64 + j * 8);
            *(uint4*)(&smem[n * 264 + 128 + dir * 64 + j * 8]) = raw;
        }
    }
    __syncthreads();

    f32x4 acc[2][4] = {};
    {
        const unsigned short* arow = &smem[(wr * 32 + l15) * 264 + l4 * 8];
        const unsigned short* bb0  = wn1t + (wc * 64 + l15) * 256 + l4 * 8;
        for (int ks = 0; ks < 8; ++ks) {
            bf16x8 a0 = *(const bf16x8*)(arow + ks * 32);
            bf16x8 a1 = *(const bf16x8*)(arow + 16 * 264 + ks * 32);
            #pragma unroll
            for (int n = 0; n < 4; ++n) {
                bf16x8 bb = *(const bf16x8*)(bb0 + n * 16 * 256 + ks * 32);
                acc[0][n] = __builtin_amdgcn_mfma_f32_16x16x32_bf16(a0, bb, acc[0][n], 0, 0, 0);
                acc[1][n] = __builtin_amdgcn_mfma_f32_16x16x32_bf16(a1, bb, acc[1][n], 0, 0, 0);
            }
        }
    }
    __syncthreads();

    #pragma unroll
    for (int n = 0; n < 4; ++n) {
        int col = wc * 64 + n * 16 + l15;
        float bias = bn1[col];
        #pragma unroll
        for (int m = 0; m < 2; ++m) {
            #pragma unroll
            for (int i = 0; i < 4; ++i) {
                int row = wr * 32 + m * 16 + l4 * 4 + i;
                float a = acc[m][n][i] + bias;
                smem[row * 136 + col] = f2bf(a / (1.f + __expf(-a)));
            }
        }
    }
    __syncthreads();

    f32x4 acc2[2][4] = {};
    {
        const unsigned short* hrow = &smem[(wr * 32 + l15) * 136 + l4 * 8];
        const unsigned short* bb0  = wn2t + (wc * 64 + l15) * 128 + l4 * 8;
        #pragma unroll
        for (int ks = 0; ks < 4; ++ks) {
            bf16x8 a0 = *(const bf16x8*)(hrow + ks * 32);
            bf16x8 a1 = *(const bf16x8*)(hrow + 16 * 136 + ks * 32);
            #pragma unroll
            for (int n = 0; n < 4; ++n) {
                bf16x8 bb = *(const bf16x8*)(bb0 + n * 16 * 128 + ks * 32);
                acc2[0][n] = __builtin_amdgcn_mfma_f32_16x16x32_bf16(a0, bb, acc2[0][n], 0, 0, 0);
                acc2[1][n] = __builtin_amdgcn_mfma_f32_16x16x32_bf16(a1, bb, acc2[1][n], 0, 0, 0);
            }
        }
    }

    #pragma unroll
    for (int n = 0; n < 4; ++n) {
        int col = wc * 64 + n * 16 + l15;
        float bias = bn2[col];
        #pragma unroll
        for (int m = 0; m < 2; ++m) {
            #pragma unroll
            for (int i = 0; i < 4; ++i) {
                long long row = nflat0 + wr * 32 + m * 16 + l4 * 4 + i;
                node_emb[row * 128 + col] = acc2[m][n][i] + bias;
            }
        }
    }
}

// ------------------------------------------------------------ attention kernel
__global__ __launch_bounds__(256)
void attn_kernel(const float* __restrict__ blocks, const float* __restrict__ node_emb,
                 const float* __restrict__ w_attn, const float* __restrict__ rms_w,
                 float* __restrict__ out)
{
    const int t    = threadIdx.x;
    const int wave = t >> 6;
    const int lane = t & 63;
    const long long node = (long long)blockIdx.x * 4 + wave;
    const int d0 = lane * 2;

    float2 wa = *(const float2*)(w_attn + d0);
    float2 rw = *(const float2*)(rms_w + d0);

    float xs[5][2];
    float lg[5];
    #pragma unroll
    for (int s = 0; s < 5; ++s) {
        const float* src = (s < 4)
            ? (blocks + ((long long)s * NBATCH * NNODES + node) * 128)
            : (node_emb + node * 128);
        float2 x = *(const float2*)(src + d0);
        xs[s][0] = x.x; xs[s][1] = x.y;
        float ss = x.x * x.x + x.y * x.y;
        float wv = wa.x * rw.x * x.x + wa.y * rw.y * x.y;
        #pragma unroll
        for (int m = 1; m < 64; m <<= 1) {
            ss += __shfl_xor(ss, m);
            wv += __shfl_xor(wv, m);
        }
        lg[s] = wv * rsqrtf(ss * (1.f / 128.f) + 1e-6f);
    }

    float mx = lg[0];
    #pragma unroll
    for (int s = 1; s < 5; ++s) mx = fmaxf(mx, lg[s]);
    float ex[5], sum = 0.f;
    #pragma unroll
    for (int s = 0; s < 5; ++s) { ex[s] = __expf(lg[s] - mx); sum += ex[s]; }
    float inv = 1.f / sum;

    float h0 = 0.f, h1 = 0.f;
    #pragma unroll
    for (int s = 0; s < 5; ++s) {
        float a = ex[s] * inv;
        h0 = fmaf(a, xs[s][0], h0);
        h1 = fmaf(a, xs[s][1], h1);
    }
    *(float2*)(out + node * 128 + d0) = make_float2(h0, h1);
}

// ------------------------------------------------------------------- launcher
extern "C" void kernel_launch(void* const* d_in, const int* in_sizes, int n_in,
                              void* d_out, int out_size, void* d_ws, size_t ws_size,
                              hipStream_t stream)
{
    const float* V      = (const float*)d_in[0];
    const float* E      = (const float*)d_in[1];
    const float* blocks = (const float*)d_in[2];
    const float* We1    = (const float*)d_in[3];
    const float* be1    = (const float*)d_in[4];
    const float* We2    = (const float*)d_in[5];
    const float* be2    = (const float*)d_in[6];
    const float* Wn1    = (const float*)d_in[7];
    const float* bn1    = (const float*)d_in[8];
    const float* Wn2    = (const float*)d_in[9];
    const float* bn2    = (const float*)d_in[10];
    const float* w_attn = (const float*)d_in[11];
    const float* rms_w  = (const float*)d_in[12];
    const int*   edges  = (const int*)d_in[13];
    float* out = (float*)d_out;

    // ws layout (~181 MB):
    // [cnt 256KB][cur 256KB][off 256KB][pos0 2MB][pos1 2MB][m0 4MB][m1 4MB]
    // [wbf 224KB][P 16.8MB][out0 67MB][out1 67MB][node_emb 16.8MB]
    int* cnti = (int*)d_ws;                         // 65536
    int* cur  = cnti + 65536;
    int* offi = cur + 65536;
    int* pos0 = offi + 65536;                       // 524288
    int* pos1 = pos0 + NBATCH * NEDGES;             // 524288
    unsigned short* m0  = (unsigned short*)(pos1 + NBATCH * NEDGES);
    unsigned short* m1  = m0 + 2097152;
    unsigned short* wbf = m1 + 2097152;             // 114688
    unsigned short* w1ef = wbf;
    unsigned short* w2f  = wbf + 16384;
    unsigned short* wp   = wbf + 32768;
    unsigned short* wn1t = wbf + 65536;
    unsigned short* wn2t = wbf + 98304;
    unsigned short* P    = wbf + 114688;            // 8388608
    unsigned short* out0 = P + 8388608;             // NBATCH*NEDGES*64
    unsigned short* out1 = out0 + (size_t)NBATCH * NEDGES * 64;
    float* node_emb = (float*)(out1 + (size_t)NBATCH * NEDGES * 64);

    // zero edge-count histogram only
    (void)hipMemsetAsync(cnti, 0, 65536 * sizeof(int), stream);

    prep_weights<<<448, 256, 0, stream>>>(We1, We2, Wn1, Wn2, wbf);

    partial_kernel<<<(NBATCH * NNODES) / 64, 256, 0, stream>>>(V, wp, P);

    // CSR build (slots, not inverse lists)
    count_kernel<<<(NBATCH * NEDGES) / 256, 256, 0, stream>>>(edges, cnti);
    scan_kernel<<<2, 1024, 0, stream>>>(cnti, offi, cur);
    fill_kernel<<<(NBATCH * NEDGES) / 256, 256, 0, stream>>>(edges, cur, pos0, pos1);

    // edge MLP writes CSR-ordered -> gather reads contiguous
    edge_kernel<<<(NBATCH * NEDGES) / TE, 512, 0, stream>>>(
        E, edges, P, w1ef, be1, w2f, pos0, pos1, out0, out1);
    gather_kernel<<<4096, 256, 0, stream>>>(
        out0, out1, offi, cnti, be2, m0, m1);

    node_kernel<<<(NBATCH * NNODES) / 64, 256, 0, stream>>>(
        V, m0, m1, wn1t, bn1, wn2t, bn2, node_emb);

    attn_kernel<<<(NBATCH * NNODES) / 4, 256, 0, stream>>>(
        blocks, node_emb, w_attn, rms_w, out);
}

// Round 19
// 361.266 us; speedup vs baseline: 1.1465x; 1.1247x over previous
//
#include <hip/hip_runtime.h>
#include <hip/hip_bf16.h>

#define D 128
#define NNODES 16384
#define NEDGES 262144
#define NBATCH 2
#define TE 128

typedef __attribute__((ext_vector_type(8))) short bf16x8;
typedef __attribute__((ext_vector_type(4))) float f32x4;

// single hardware instruction: packs 2 f32 -> 2 bf16 (RNE)
__device__ __forceinline__ unsigned int pk2bf(float lo, float hi) {
    unsigned int r;
    asm("v_cvt_pk_bf16_f32 %0, %1, %2" : "=v"(r) : "v"(lo), "v"(hi));
    return r;
}

__device__ __forceinline__ unsigned short f2bf(float f) {
    return (unsigned short)pk2bf(f, f);
}

__device__ __forceinline__ float bflo(unsigned int u) {
    return __uint_as_float(u << 16);
}
__device__ __forceinline__ float bfhi(unsigned int u) {
    return __uint_as_float(u & 0xffff0000u);
}

__device__ __forceinline__ bf16x8 pack8(f32x4 a, f32x4 b) {
    typedef __attribute__((ext_vector_type(4))) unsigned int u32x4;
    u32x4 u;
    u.x = pk2bf(a[0], a[1]);
    u.y = pk2bf(a[2], a[3]);
    u.z = pk2bf(b[0], b[1]);
    u.w = pk2bf(b[2], b[3]);
    return __builtin_bit_cast(bf16x8, u);
}

// memory-side packed bf16 atomic add (2 cols per dword-RMW)
__device__ __forceinline__ void atomic_pk(unsigned int* p, unsigned int v) {
    asm volatile("global_atomic_pk_add_bf16 %0, %1, off" :: "v"(p), "v"(v) : "memory");
}

// --------------------------------------------------------------- weight prep
__global__ __launch_bounds__(256)
void prep_weights(const float* __restrict__ We1, const float* __restrict__ We2,
                  const float* __restrict__ Wn1, const float* __restrict__ Wn2,
                  unsigned short* __restrict__ w)
{
    int id = blockIdx.x * 256 + threadIdx.x;   // 114688 total
    if (id < 16384) {
        int e = id & 7, l = (id >> 3) & 63, nblk = (id >> 9) & 7, ks = id >> 12;
        int k = 256 + ks * 32 + ((l >> 4) & 3) * 8 + e;
        int col = nblk * 16 + (l & 15);
        w[id] = f2bf(We1[k * 128 + col]);
    } else if (id < 32768) {
        int i2 = id - 16384;
        int e = i2 & 7, l = (i2 >> 3) & 63, nblk = (i2 >> 9) & 7, ks = i2 >> 12;
        int k = ks * 32 + ((l >> 4) & 3) * 8 + e;
        int col = nblk * 16 + (l & 15);
        w[id] = f2bf(We2[k * 128 + col]);
    } else if (id < 65536) {
        int i3 = id - 32768;
        int j = i3 >> 7, k = i3 & 127;
        int row = (j < 128) ? k : (128 + k);
        w[id] = f2bf(We1[row * 128 + (j & 127)]);
    } else if (id < 98304) {
        int i4 = id - 65536;
        int n = i4 >> 8, k = i4 & 255;
        w[id] = f2bf(Wn1[k * 128 + n]);
    } else {
        int i5 = id - 98304;
        int n = i5 >> 7, k = i5 & 127;
        w[id] = f2bf(Wn2[k * 128 + n]);
    }
}

// ------------------------------------------------------------ partial kernel
// P2[r][pcol]: PERMUTED layout: original col = part*128 + sub*64 + n*16 + l15
// stored at part*128 + sub*64 + l15*4 + n
__global__ __launch_bounds__(256)
void partial_kernel(const float* __restrict__ V, const unsigned short* __restrict__ wp,
                    unsigned short* __restrict__ P)
{
    __shared__ unsigned short smem[64 * 136];
    const int t = threadIdx.x, lane = t & 63, wave = t >> 6;
    const int l15 = lane & 15, l4 = lane >> 4;
    const long long r0 = (long long)blockIdx.x * 64;

    for (int i = t; i < 64 * 32; i += 256) {
        int c4 = i & 31, r = i >> 5;
        float4 v = *(const float4*)(V + (r0 + r) * 128 + c4 * 4);
        uint2 p; p.x = pk2bf(v.x, v.y); p.y = pk2bf(v.z, v.w);
        *(uint2*)(&smem[r * 136 + c4 * 4]) = p;
    }
    __syncthreads();

    const int j0 = wave * 64;
    f32x4 acc[4][4] = {};
    const unsigned short* bb0 = wp + (j0 + l15) * 128 + l4 * 8;
    #pragma unroll
    for (int ks = 0; ks < 4; ++ks) {
        bf16x8 bb[4];
        #pragma unroll
        for (int n = 0; n < 4; ++n)
            bb[n] = *(const bf16x8*)(bb0 + n * 16 * 128 + ks * 32);
        #pragma unroll
        for (int mq = 0; mq < 4; ++mq) {
            bf16x8 a = *(const bf16x8*)(&smem[(mq * 16 + l15) * 136 + l4 * 8 + ks * 32]);
            #pragma unroll
            for (int n = 0; n < 4; ++n)
                acc[mq][n] = __builtin_amdgcn_mfma_f32_16x16x32_bf16(a, bb[n], acc[mq][n], 0, 0, 0);
        }
    }
    const int pbase = (wave >> 1) * 128 + (wave & 1) * 64 + l15 * 4;
    #pragma unroll
    for (int mq = 0; mq < 4; ++mq) {
        #pragma unroll
        for (int i = 0; i < 4; ++i) {
            int row = mq * 16 + l4 * 4 + i;
            uint2 pw;
            pw.x = pk2bf(acc[mq][0][i], acc[mq][1][i]);
            pw.y = pk2bf(acc[mq][2][i], acc[mq][3][i]);
            *(uint2*)(P + (r0 + row) * 256 + pbase) = pw;
        }
    }
}

// ---------------------------------------------------------------- edge kernel
// 128 edges/block, 8 waves, 512 threads. P-gather issued BEFORE the layer-1
// MFMA loop (only depends on edge indices) so L3 gather latency hides under
// MFMA1 + cvt. All f32->bf16 via v_cvt_pk_bf16_f32. Single barrier.
// Scatter: packed-bf16 memory-side atomics (xor-1 lane pairs).
__global__ __launch_bounds__(512)
void edge_kernel(const float* __restrict__ E, const int* __restrict__ edges,
                 const unsigned short* __restrict__ P,
                 const unsigned short* __restrict__ w1ef, const float* __restrict__ be1,
                 const unsigned short* __restrict__ w2f,
                 unsigned short* __restrict__ us_m0, unsigned short* __restrict__ us_m1,
                 float* __restrict__ c0, float* __restrict__ c1)
{
    __shared__ unsigned short Hbuf[TE * 136];

    const int t    = threadIdx.x;
    const int lane = t & 63;
    const int wave = t >> 6;
    const int wr   = wave >> 1;          // 0..3 (32-edge row block)
    const int wc   = wave & 1;           // 0..1 (64-col block)
    const int l15  = lane & 15;
    const int l4   = lane >> 4;

    const long long eflat0 = (long long)blockIdx.x * TE;
    const int b  = (int)(eflat0 / NEDGES);
    const long long nb0 = (long long)b * NNODES;

    // degree counts
    if (t < TE) {
        int2 e2 = *(const int2*)(edges + (eflat0 + t) * 2);
        atomicAdd(&c0[nb0 + e2.x], 1.f);
        atomicAdd(&c1[nb0 + e2.y], 1.f);
    }

    // ---- node indices first (needed by the P gather) ----
    int nd0[2][4], nd1[2][4];
    #pragma unroll
    for (int m = 0; m < 2; ++m) {
        #pragma unroll
        for (int i = 0; i < 4; ++i) {
            int row = wr * 32 + m * 16 + l4 * 4 + i;
            int2 e2 = *(const int2*)(edges + (eflat0 + row) * 2);
            nd0[m][i] = e2.x;
            nd1[m][i] = e2.y;
        }
    }

    // ---- P gather issued EARLY: latency hides under MFMA1 below ----
    const unsigned short* Pb = P + nb0 * 256;
    const unsigned int wcl = wc * 64 + l15 * 4;
    uint2 su[2][4], ru[2][4];
    #pragma unroll
    for (int m = 0; m < 2; ++m) {
        #pragma unroll
        for (int i = 0; i < 4; ++i) {
            su[m][i] = *(const uint2*)(Pb + (unsigned)nd0[m][i] * 256u + wcl);
            ru[m][i] = *(const uint2*)(Pb + (unsigned)nd1[m][i] * 256u + 128u + wcl);
        }
    }

    // ---- layer 1 (E part): [128x128] @ [128x128], A direct from global ----
    f32x4 acc[2][4] = {};
    {
        const float* er0 = E + (eflat0 + wr * 32 + l15) * D + l4 * 8;
        #pragma unroll
        for (int ks = 0; ks < 4; ++ks) {
            f32x4 xa0 = *(const f32x4*)(er0 + ks * 32);
            f32x4 xb0 = *(const f32x4*)(er0 + ks * 32 + 4);
            f32x4 xa1 = *(const f32x4*)(er0 + 16 * D + ks * 32);
            f32x4 xb1 = *(const f32x4*)(er0 + 16 * D + ks * 32 + 4);
            bf16x8 a0 = pack8(xa0, xb0);
            bf16x8 a1 = pack8(xa1, xb1);
            #pragma unroll
            for (int n = 0; n < 4; ++n) {
                bf16x8 bb = *(const bf16x8*)(w1ef + (((ks * 8 + wc * 4 + n) * 64 + lane) << 3));
                acc[0][n] = __builtin_amdgcn_mfma_f32_16x16x32_bf16(a0, bb, acc[0][n], 0, 0, 0);
                acc[1][n] = __builtin_amdgcn_mfma_f32_16x16x32_bf16(a1, bb, acc[1][n], 0, 0, 0);
            }
        }
    }

    // epilogue: + P_s + P_r + bias, silu -> Hbuf
    float bia[4];
    #pragma unroll
    for (int n = 0; n < 4; ++n) bia[n] = be1[wc * 64 + n * 16 + l15];
    #pragma unroll
    for (int m = 0; m < 2; ++m) {
        #pragma unroll
        for (int i = 0; i < 4; ++i) {
            int row = wr * 32 + m * 16 + l4 * 4 + i;
            float ps[4] = { bflo(su[m][i].x), bfhi(su[m][i].x),
                            bflo(su[m][i].y), bfhi(su[m][i].y) };
            float pr[4] = { bflo(ru[m][i].x), bfhi(ru[m][i].x),
                            bflo(ru[m][i].y), bfhi(ru[m][i].y) };
            #pragma unroll
            for (int n = 0; n < 4; ++n) {
                float a = acc[m][n][i] + bia[n] + ps[n] + pr[n];
                Hbuf[row * 136 + wc * 64 + n * 16 + l15] = f2bf(a / (1.f + __expf(-a)));
            }
        }
    }
    __syncthreads();   // single barrier: H handoff

    // ---- layer 2: [128x128] @ [128x128] ----
    f32x4 acc2[2][4] = {};
    {
        const unsigned short* hrow = &Hbuf[(wr * 32 + l15) * 136 + l4 * 8];
        #pragma unroll
        for (int ks = 0; ks < 4; ++ks) {
            bf16x8 a0 = *(const bf16x8*)(hrow + ks * 32);
            bf16x8 a1 = *(const bf16x8*)(hrow + 16 * 136 + ks * 32);
            #pragma unroll
            for (int n = 0; n < 4; ++n) {
                bf16x8 bb = *(const bf16x8*)(w2f + (((ks * 8 + wc * 4 + n) * 64 + lane) << 3));
                acc2[0][n] = __builtin_amdgcn_mfma_f32_16x16x32_bf16(a0, bb, acc2[0][n], 0, 0, 0);
                acc2[1][n] = __builtin_amdgcn_mfma_f32_16x16x32_bf16(a1, bb, acc2[1][n], 0, 0, 0);
            }
        }
    }

    // scatter: packed bf16 atomics. xor-1 lane pair = same edge, adjacent
    // cols; even lane adds (col, col+1) in one dword-RMW. be2 deferred to
    // node kernel (mean(x+b)=mean(x)+b, count-gated there).
    {
        unsigned short* dst_arr = wc ? us_m1 : us_m0;
        #pragma unroll
        for (int n = 0; n < 4; ++n) {
            int colh = n * 16 + l15;
            #pragma unroll
            for (int m = 0; m < 2; ++m) {
                #pragma unroll
                for (int i = 0; i < 4; ++i) {
                    int node = wc ? nd1[m][i] : nd0[m][i];
                    float v  = acc2[m][n][i];
                    float vn = __shfl_xor(v, 1);
                    if (!(lane & 1)) {
                        atomic_pk((unsigned int*)(dst_arr + (nb0 + node) * 64 + colh),
                                  pk2bf(v, vn));
                    }
                }
            }
        }
    }
}

// ---------------------------------------------------------------- node kernel
// m0/m1 bf16 sums; divide by count and add be2 (count-gated) at staging.
__global__ __launch_bounds__(256)
void node_kernel(const float* __restrict__ V,
                 const unsigned short* __restrict__ m0, const unsigned short* __restrict__ m1,
                 const float* __restrict__ c0, const float* __restrict__ c1,
                 const float* __restrict__ be2,
                 const unsigned short* __restrict__ wn1t, const float* __restrict__ bn1,
                 const unsigned short* __restrict__ wn2t, const float* __restrict__ bn2,
                 float* __restrict__ node_emb)
{
    __shared__ unsigned short smem[64 * 264];   // A [64][264]; reused as H [64][136]

    const int t    = threadIdx.x;
    const int lane = t & 63;
    const int wave = t >> 6;
    const int wr   = wave >> 1;
    const int wc   = wave & 1;
    const int l15  = lane & 15;
    const int l4   = lane >> 4;

    const long long nflat0 = (long long)blockIdx.x * 64;

    for (int i = t; i < 64 * 48; i += 256) {
        int n  = i / 48;
        int c4 = i - n * 48;
        long long node = nflat0 + n;
        if (c4 < 32) {
            float4 v = *(const float4*)(V + node * 128 + c4 * 4);
            uint2 p; p.x = pk2bf(v.x, v.y); p.y = pk2bf(v.z, v.w);
            *(uint2*)(&smem[n * 264 + c4 * 4]) = p;
        } else {
            int dir = (c4 >= 40);
            int j = c4 - 32 - dir * 8;
            const unsigned short* src = dir ? m1 : m0;
            float cnt = (dir ? c1 : c0)[node];
            float inv = 1.f / fmaxf(cnt, 1.f);
            float bon = (cnt >= 1.f) ? 1.f : 0.f;     // zero-degree: mean=0, no bias
            uint4 raw = *(const uint4*)(src + node * 64 + j * 8);
            const float* bb = be2 + dir * 64 + j * 8;
            unsigned int rr[4] = {raw.x, raw.y, raw.z, raw.w};
            unsigned int o[4];
            #pragma unroll
            for (int q = 0; q < 4; ++q) {
                float lo = bflo(rr[q]) * inv + bb[2 * q] * bon;
                float hi = bfhi(rr[q]) * inv + bb[2 * q + 1] * bon;
                o[q] = pk2bf(lo, hi);
            }
            uint4 st; st.x = o[0]; st.y = o[1]; st.z = o[2]; st.w = o[3];
            *(uint4*)(&smem[n * 264 + 128 + dir * 64 + j * 8]) = st;
        }
    }
    __syncthreads();

    f32x4 acc[2][4] = {};
    {
        const unsigned short* arow = &smem[(wr * 32 + l15) * 264 + l4 * 8];
        const unsigned short* bb0  = wn1t + (wc * 64 + l15) * 256 + l4 * 8;
        for (int ks = 0; ks < 8; ++ks) {
            bf16x8 a0 = *(const bf16x8*)(arow + ks * 32);
            bf16x8 a1 = *(const bf16x8*)(arow + 16 * 264 + ks * 32);
            #pragma unroll
            for (int n = 0; n < 4; ++n) {
                bf16x8 bb = *(const bf16x8*)(bb0 + n * 16 * 256 + ks * 32);
                acc[0][n] = __builtin_amdgcn_mfma_f32_16x16x32_bf16(a0, bb, acc[0][n], 0, 0, 0);
                acc[1][n] = __builtin_amdgcn_mfma_f32_16x16x32_bf16(a1, bb, acc[1][n], 0, 0, 0);
            }
        }
    }
    __syncthreads();

    #pragma unroll
    for (int n = 0; n < 4; ++n) {
        int col = wc * 64 + n * 16 + l15;
        float bias = bn1[col];
        #pragma unroll
        for (int m = 0; m < 2; ++m) {
            #pragma unroll
            for (int i = 0; i < 4; ++i) {
                int row = wr * 32 + m * 16 + l4 * 4 + i;
                float a = acc[m][n][i] + bias;
                smem[row * 136 + col] = f2bf(a / (1.f + __expf(-a)));
            }
        }
    }
    __syncthreads();

    f32x4 acc2[2][4] = {};
    {
        const unsigned short* hrow = &smem[(wr * 32 + l15) * 136 + l4 * 8];
        const unsigned short* bb0  = wn2t + (wc * 64 + l15) * 128 + l4 * 8;
        #pragma unroll
        for (int ks = 0; ks < 4; ++ks) {
            bf16x8 a0 = *(const bf16x8*)(hrow + ks * 32);
            bf16x8 a1 = *(const bf16x8*)(hrow + 16 * 136 + ks * 32);
            #pragma unroll
            for (int n = 0; n < 4; ++n) {
                bf16x8 bb = *(const bf16x8*)(bb0 + n * 16 * 128 + ks * 32);
                acc2[0][n] = __builtin_amdgcn_mfma_f32_16x16x32_bf16(a0, bb, acc2[0][n], 0, 0, 0);
                acc2[1][n] = __builtin_amdgcn_mfma_f32_16x16x32_bf16(a1, bb, acc2[1][n], 0, 0, 0);
            }
        }
    }

    #pragma unroll
    for (int n = 0; n < 4; ++n) {
        int col = wc * 64 + n * 16 + l15;
        float bias = bn2[col];
        #pragma unroll
        for (int m = 0; m < 2; ++m) {
            #pragma unroll
            for (int i = 0; i < 4; ++i) {
                long long row = nflat0 + wr * 32 + m * 16 + l4 * 4 + i;
                node_emb[row * 128 + col] = acc2[m][n][i] + bias;
            }
        }
    }
}

// ------------------------------------------------------------ attention kernel
__global__ __launch_bounds__(256)
void attn_kernel(const float* __restrict__ blocks, const float* __restrict__ node_emb,
                 const float* __restrict__ w_attn, const float* __restrict__ rms_w,
                 float* __restrict__ out)
{
    const int t    = threadIdx.x;
    const int wave = t >> 6;
    const int lane = t & 63;
    const long long node = (long long)blockIdx.x * 4 + wave;
    const int d0 = lane * 2;

    float2 wa = *(const float2*)(w_attn + d0);
    float2 rw = *(const float2*)(rms_w + d0);

    float xs[5][2];
    float lg[5];
    #pragma unroll
    for (int s = 0; s < 5; ++s) {
        const float* src = (s < 4)
            ? (blocks + ((long long)s * NBATCH * NNODES + node) * 128)
            : (node_emb + node * 128);
        float2 x = *(const float2*)(src + d0);
        xs[s][0] = x.x; xs[s][1] = x.y;
        float ss = x.x * x.x + x.y * x.y;
        float wv = wa.x * rw.x * x.x + wa.y * rw.y * x.y;
        #pragma unroll
        for (int m = 1; m < 64; m <<= 1) {
            ss += __shfl_xor(ss, m);
            wv += __shfl_xor(wv, m);
        }
        lg[s] = wv * rsqrtf(ss * (1.f / 128.f) + 1e-6f);
    }

    float mx = lg[0];
    #pragma unroll
    for (int s = 1; s < 5; ++s) mx = fmaxf(mx, lg[s]);
    float ex[5], sum = 0.f;
    #pragma unroll
    for (int s = 0; s < 5; ++s) { ex[s] = __expf(lg[s] - mx); sum += ex[s]; }
    float inv = 1.f / sum;

    float h0 = 0.f, h1 = 0.f;
    #pragma unroll
    for (int s = 0; s < 5; ++s) {
        float a = ex[s] * inv;
        h0 = fmaf(a, xs[s][0], h0);
        h1 = fmaf(a, xs[s][1], h1);
    }
    *(float2*)(out + node * 128 + d0) = make_float2(h0, h1);
}

// ------------------------------------------------------------------- launcher
extern "C" void kernel_launch(void* const* d_in, const int* in_sizes, int n_in,
                              void* d_out, int out_size, void* d_ws, size_t ws_size,
                              hipStream_t stream)
{
    const float* V      = (const float*)d_in[0];
    const float* E      = (const float*)d_in[1];
    const float* blocks = (const float*)d_in[2];
    const float* We1    = (const float*)d_in[3];
    const float* be1    = (const float*)d_in[4];
    const float* We2    = (const float*)d_in[5];
    const float* be2    = (const float*)d_in[6];
    const float* Wn1    = (const float*)d_in[7];
    const float* bn1    = (const float*)d_in[8];
    const float* Wn2    = (const float*)d_in[9];
    const float* bn2    = (const float*)d_in[10];
    const float* w_attn = (const float*)d_in[11];
    const float* rms_w  = (const float*)d_in[12];
    const int*   edges  = (const int*)d_in[13];
    float* out = (float*)d_out;

    // ws layout: [us_m0 bf16 4MB][us_m1 bf16 4MB][c0 128KB][c1 128KB]
    //            [node_emb f32 16MB][wbf 224KB][P bf16 16.8MB]
    unsigned short* us_m0 = (unsigned short*)d_ws;          // 2097152 ushort
    unsigned short* us_m1 = us_m0 + 2097152;
    float* c0       = (float*)(us_m1 + 2097152);
    float* c1       = c0 + 32768;
    float* node_emb = c1 + 32768;
    unsigned short* wbf = (unsigned short*)(node_emb + 4194304);  // 114688 bf16
    unsigned short* w1ef = wbf;            // 16384 (frag-ordered We1 E-part)
    unsigned short* w2f  = wbf + 16384;    // 16384 (frag-ordered We2)
    unsigned short* wp   = wbf + 32768;    // 32768 ([W1s|W1r] transposed)
    unsigned short* wn1t = wbf + 65536;    // 32768
    unsigned short* wn2t = wbf + 98304;    // 16384
    unsigned short* P    = wbf + 114688;   // 32768*256 bf16 partials (16.8MB)

    // zero bf16 accumulators + counts (8MB + 256KB)
    (void)hipMemsetAsync(d_ws, 0, (size_t)(2097152 * 2 * 2 + 32768 * 2 * 4), stream);

    prep_weights<<<448, 256, 0, stream>>>(We1, We2, Wn1, Wn2, wbf);

    partial_kernel<<<(NBATCH * NNODES) / 64, 256, 0, stream>>>(V, wp, P);

    edge_kernel<<<(NBATCH * NEDGES) / TE, 512, 0, stream>>>(
        E, edges, P, w1ef, be1, w2f, us_m0, us_m1, c0, c1);

    node_kernel<<<(NBATCH * NNODES) / 64, 256, 0, stream>>>(
        V, us_m0, us_m1, c0, c1, be2, wn1t, bn1, wn2t, bn2, node_emb);

    attn_kernel<<<(NBATCH * NNODES) / 4, 256, 0, stream>>>(
        blocks, node_emb, w_attn, rms_w, out);
}